// Round 14
// baseline (208.161 us; speedup 1.0000x reference)
//
#include <hip/hip_runtime.h>
#include <hip/hip_fp16.h>

#define MM 2048
#define NN 2048
#define DD 512
#define NA 2049        // augmented dim (m+1 = n+1)
#define LDH 2056       // fp16 padded row stride (4112 B, 16B-aligned)
#define LDE 1024       // split-bf16 row stride ([hi(512) | lo(512)])
#define ITERS 100
#define NWG 257        // persistent grid (proven config)
#define TPB 512

typedef __attribute__((ext_vector_type(8))) short short8;
typedef __attribute__((ext_vector_type(4))) float f32x4;

__device__ __forceinline__ unsigned short f2bf(float x) {
    unsigned u = __builtin_bit_cast(unsigned, x);
    u += 0x7FFFu + ((u >> 16) & 1u);          // round-to-nearest-even
    return (unsigned short)(u >> 16);
}
__device__ __forceinline__ float bf2f(unsigned short h) {
    unsigned u = ((unsigned)h) << 16;
    return __builtin_bit_cast(float, u);
}
__device__ __forceinline__ void gload_lds16(const void* g, void* l) {
    __builtin_amdgcn_global_load_lds(
        (const __attribute__((address_space(1))) void*)g,
        (__attribute__((address_space(3))) void*)l, 16, 0, 0);
}

// ---------------------------------------------------------------------------
// fused init + split: blocks x<1024 split f32 -> bf16 hi|lo; x>=1024 init
// augmented row/col of K0, K0hT, Kreg + c=1 + ctrl (slots/release/chg) zeroing
// ---------------------------------------------------------------------------
__global__ __launch_bounds__(256) void init_split(const float* __restrict__ Q,
                                                  const float* __restrict__ Rm,
                                                  ushort* __restrict__ Qe,
                                                  ushort* __restrict__ Re,
                                                  float* __restrict__ Kreg,
                                                  _Float16* __restrict__ K0h,
                                                  _Float16* __restrict__ K0hT,
                                                  float* __restrict__ c,
                                                  unsigned* __restrict__ ctrl,
                                                  const float* __restrict__ zp) {
    if (blockIdx.x < 1024) {
        const float* src = blockIdx.y ? Rm : Q;
        ushort* dst = blockIdx.y ? Re : Qe;
        int e4 = blockIdx.x * 256 + threadIdx.x;    // float4 units
        int row = e4 >> 7;
        int c4 = (e4 & 127) * 4;
        float4 v = *(const float4*)(src + (size_t)row * DD + c4);
        ushort4 hi, lo;
        hi.x = f2bf(v.x); lo.x = f2bf(v.x - bf2f(hi.x));
        hi.y = f2bf(v.y); lo.y = f2bf(v.y - bf2f(hi.y));
        hi.z = f2bf(v.z); lo.z = f2bf(v.z - bf2f(hi.z));
        hi.w = f2bf(v.w); lo.w = f2bf(v.w - bf2f(hi.w));
        *(ushort4*)(dst + (size_t)row * LDE + c4) = hi;
        *(ushort4*)(dst + (size_t)row * LDE + 512 + c4) = lo;
    } else {
        float e5 = expf(zp[0] * 10.0f);   // exp(z/eps)
        int idx = (blockIdx.x - 1024) * 512 + blockIdx.y * 256 + threadIdx.x;
        for (int t = idx; t < NA; t += 1024) {
            if (t < 1024) ctrl[t] = 0u;   // slots[0..255], rel[256..511], chg[512..]
            c[t] = 1.0f;
            Kreg[(size_t)2048 * NA + t] = e5;
            K0h [(size_t)2048 * LDH + t] = (_Float16)e5;
            K0hT[(size_t)2048 * LDH + t] = (_Float16)e5;
            if (t < MM) {
                Kreg[(size_t)t * NA + 2048] = e5;
                K0h [(size_t)t * LDH + 2048] = (_Float16)e5;
                K0hT[(size_t)t * LDH + 2048] = (_Float16)e5;
            }
        }
    }
}

// ---------------------------------------------------------------------------
// bf16 MFMA GEMM over K'=1024 (hi|lo concat) + exp epilogue.
// Writes f32 Kreg, fp16 K0h, AND fp16 K0hT (fused transpose).  [verified r5-13]
// ---------------------------------------------------------------------------
__global__ __launch_bounds__(256, 2) void gemm_mfma(const ushort* __restrict__ Ae,
                                                    const ushort* __restrict__ Be,
                                                    float* __restrict__ Kreg,
                                                    _Float16* __restrict__ K0h,
                                                    _Float16* __restrict__ K0hT) {
    __shared__ ushort Als[64 * 32];
    __shared__ ushort Bls[128 * 32];
    const int tid = threadIdx.x;
    const int wid = tid >> 6, lane = tid & 63;
    const int row0 = blockIdx.y * 64, col0 = blockIdx.x * 128;
    const int wr = wid >> 1, wc = wid & 1;

    const int sr = lane >> 2, sc = (lane & 3) * 8;
    const ushort* gA  = Ae + (size_t)(row0 + wid * 16 + sr) * LDE + sc;
    const ushort* gB0 = Be + (size_t)(col0 + wid * 16 + sr) * LDE + sc;
    const ushort* gB1 = Be + (size_t)(col0 + 64 + wid * 16 + sr) * LDE + sc;
    ushort* lA  = &Als[wid * 16 * 32];
    ushort* lB0 = &Bls[wid * 16 * 32];
    ushort* lB1 = &Bls[(64 + wid * 16) * 32];

    f32x4 acc[2][4] = {};
    const int fr = lane & 15, fk = (lane >> 4) * 8;

    for (int k0 = 0; k0 < 1024; k0 += 32) {
        __syncthreads();
        gload_lds16(gA + k0, lA);
        gload_lds16(gB0 + k0, lB0);
        gload_lds16(gB1 + k0, lB1);
        __syncthreads();
        short8 a[2], b[4];
#pragma unroll
        for (int mi = 0; mi < 2; ++mi)
            a[mi] = *(const short8*)&Als[(wr * 32 + mi * 16 + fr) * 32 + fk];
#pragma unroll
        for (int ni = 0; ni < 4; ++ni)
            b[ni] = *(const short8*)&Bls[(wc * 64 + ni * 16 + fr) * 32 + fk];
#pragma unroll
        for (int mi = 0; mi < 2; ++mi)
#pragma unroll
            for (int ni = 0; ni < 4; ++ni)
                acc[mi][ni] = __builtin_amdgcn_mfma_f32_16x16x32_bf16(
                    a[mi], b[ni], acc[mi][ni], 0, 0, 0);
    }

#pragma unroll
    for (int mi = 0; mi < 2; ++mi)
#pragma unroll
        for (int ni = 0; ni < 4; ++ni) {
            const int rowb = row0 + wr * 32 + mi * 16 + (lane >> 4) * 4;
            const int col  = col0 + wc * 64 + ni * 16 + fr;
            union { ushort4 u; _Float16 h[4]; } tp;
#pragma unroll
            for (int q = 0; q < 4; ++q) {
                float v = expf(acc[mi][ni][q] * 10.0f);
                Kreg[(size_t)(rowb + q) * NA + col] = v;
                _Float16 hv = (_Float16)v;
                K0h[(size_t)(rowb + q) * LDH + col] = hv;
                tp.h[q] = hv;
            }
            *(ushort4*)(K0hT + (size_t)col * LDH + rowb) = tp.u;  // 8B, aligned
        }
}

// ---------------------------------------------------------------------------
// persistent Sinkhorn loop — r10 structure; ONE change: flat-arrival barrier
// with last-arriver release FAN-OUT to 8 padded lines (splits the 257-poller
// storm into 8x ~32). Check+break+chg byte-for-byte; fused finalize unchanged.
// ---------------------------------------------------------------------------
__device__ __forceinline__ void grid_barrier(unsigned* slot, unsigned* rel,
                                             unsigned ev) {
    __syncthreads();
    if (threadIdx.x == 0) {
        unsigned old = __hip_atomic_fetch_add(slot, 1u, __ATOMIC_ACQ_REL,
                                              __HIP_MEMORY_SCOPE_AGENT);
        if (old == (unsigned)NWG - 1u) {
            // last arriver: fan out the monotone epoch to 8 padded lines
#pragma unroll
            for (int g = 0; g < 8; ++g)
                __hip_atomic_store(&rel[g << 5], ev, __ATOMIC_RELEASE,
                                   __HIP_MEMORY_SCOPE_AGENT);
        } else {
            while (__hip_atomic_load(&rel[(blockIdx.x & 7) << 5],
                                     __ATOMIC_ACQUIRE,
                                     __HIP_MEMORY_SCOPE_AGENT) < ev)
                __builtin_amdgcn_s_sleep(1);
        }
    }
    __syncthreads();
}

__device__ __forceinline__ float rowdot(const _Float16* __restrict__ Krow,
                                        const float* v, int lane) {
    float sum = 0.0f;
#pragma unroll
    for (int s = 0; s < 4; ++s) {
        const int j = (s * 64 + lane) * 8;
        union { uint4 u; _Float16 h[8]; } kv;
        kv.u = *(const uint4*)(Krow + j);
        float4 c0 = *(const float4*)(v + j);
        float4 c1 = *(const float4*)(v + j + 4);
        sum += (float)kv.h[0] * c0.x + (float)kv.h[1] * c0.y +
               (float)kv.h[2] * c0.z + (float)kv.h[3] * c0.w +
               (float)kv.h[4] * c1.x + (float)kv.h[5] * c1.y +
               (float)kv.h[6] * c1.z + (float)kv.h[7] * c1.w;
    }
    if (lane == 0) sum += (float)Krow[2048] * v[2048];
#pragma unroll
    for (int off = 32; off; off >>= 1) sum += __shfl_xor(sum, off, 64);
    return sum;
}

__global__ __launch_bounds__(TPB) void sinkhorn_persist(
    const _Float16* __restrict__ K0h, const _Float16* __restrict__ K0hT,
    float* r, float* c, unsigned* slots, unsigned* rel, unsigned* chg,
    float* __restrict__ Kreg, float* __restrict__ P)
{
    const int wave = threadIdx.x >> 6, lane = threadIdx.x & 63;
    const int row = blockIdx.x * 8 + wave;
    const bool active = row < NA;
    const _Float16* KrowA = K0h  + (size_t)row * LDH;
    const _Float16* KrowB = K0hT + (size_t)row * LDH;
    __shared__ int ls_chg, ls_exit;
    float c_prev = 1.0f;

    for (int it = 0; it < ITERS; ++it) {
        if (threadIdx.x == 0) ls_chg = 0;
        // phase 1: r = 1 / (K0 c)
        if (active) {
            float s = rowdot(KrowA, c, lane);
            if (lane == 0) r[row] = 1.0f / s;
        }
        grid_barrier(&slots[2 * it], rel, 2u * it + 1u);
        // phase 2: c = 1 / (K0^T r)
        float cv = 0.0f;
        if (active) {
            float s = rowdot(KrowB, r, lane);
            cv = 1.0f / s;
            if (lane == 0) c[row] = cv;
        }
        if (active && lane == 0) {
            if (fabsf(cv - c_prev) > 1e-6f * fabsf(c_prev)) ls_chg = 1;
            c_prev = cv;
        }
        __syncthreads();
        if (threadIdx.x == 0 && ls_chg)
            __hip_atomic_fetch_or(&chg[it], 1u, __ATOMIC_RELAXED,
                                  __HIP_MEMORY_SCOPE_AGENT);
        grid_barrier(&slots[2 * it + 1], rel, 2u * it + 2u);
        if (threadIdx.x == 0)
            ls_exit = (__hip_atomic_load(&chg[it], __ATOMIC_RELAXED,
                                         __HIP_MEMORY_SCOPE_AGENT) == 0u);
        __syncthreads();
        if (ls_exit) break;
    }

    // ---- fused finalize: K = diag(r) K0 diag(c), P = K[:M,:N] ----
    if (active) {
        const float rs = r[row];
        float* krow = Kreg + (size_t)row * NA;
        float* prow = P + (size_t)row * NN;
        if (row < MM) {
            for (int col = lane; col < NN; col += 64) {
                float v = krow[col] * rs * c[col];
                krow[col] = v;
                prow[col] = v;
            }
            if (lane == 0) krow[2048] = krow[2048] * rs * c[2048];
        } else {
            for (int col = lane; col < NA; col += 64)
                krow[col] = krow[col] * rs * c[col];
        }
    }
}

// ---------------------------------------------------------------------------
extern "C" void kernel_launch(void* const* d_in, const int* in_sizes, int n_in,
                              void* d_out, int out_size, void* d_ws, size_t ws_size,
                              hipStream_t stream) {
    const float* Q  = (const float*)d_in[0];
    const float* Rm = (const float*)d_in[1];
    const float* zp = (const float*)d_in[2];

    float* P    = (float*)d_out;
    float* Kreg = P + (size_t)MM * NN;

    ushort* Qe = (ushort*)d_out;                 // staged in P region (dead by epilogue)
    ushort* Re = Qe + (size_t)2048 * LDE;

    char* ws = (char*)d_ws;
    const size_t HBYTES = 8425728;               // NA*LDH*2 rounded to 256
    _Float16* K0h  = (_Float16*)ws;
    _Float16* K0hT = (_Float16*)(ws + HBYTES);
    float* c = (float*)(ws + 2 * HBYTES);
    float* r = c + 2560;
    unsigned* ctrl = (unsigned*)(r + 2560);      // 1024 words zeroed by init
    unsigned* slots = ctrl;                      // [0..255]   barrier slots
    unsigned* rel   = ctrl + 256;                // [256..511] 8 release lines x 32
    unsigned* chg   = ctrl + 512;                // [512..611] per-iter flags

    init_split<<<dim3(1026, 2), dim3(256), 0, stream>>>(Q, Rm, Qe, Re, Kreg,
                                                        K0h, K0hT, c, ctrl, zp);
    gemm_mfma<<<dim3(16, 32), dim3(256), 0, stream>>>(Qe, Re, Kreg, K0h, K0hT);
    sinkhorn_persist<<<dim3(NWG), dim3(TPB), 0, stream>>>(K0h, K0hT, r, c,
                                                          slots, rel, chg,
                                                          Kreg, P);
}

// Round 15
// 109.374 us; speedup vs baseline: 1.9032x; 1.9032x over previous
//
#include <hip/hip_runtime.h>
#include <hip/hip_fp16.h>

#define MM 2048
#define NN 2048
#define DD 512
#define NA 2049        // augmented dim (m+1 = n+1)
#define LDH 2056       // fp16 padded row stride (4112 B, 16B-aligned)
#define LDE 1024       // split-bf16 row stride ([hi(512) | lo(512)])
#define ITERS 100
#define NWG 257        // persistent grid (proven config)
#define TPB 512

typedef __attribute__((ext_vector_type(8))) short short8;
typedef __attribute__((ext_vector_type(4))) float f32x4;

__device__ __forceinline__ unsigned short f2bf(float x) {
    unsigned u = __builtin_bit_cast(unsigned, x);
    u += 0x7FFFu + ((u >> 16) & 1u);          // round-to-nearest-even
    return (unsigned short)(u >> 16);
}
__device__ __forceinline__ float bf2f(unsigned short h) {
    unsigned u = ((unsigned)h) << 16;
    return __builtin_bit_cast(float, u);
}
__device__ __forceinline__ void gload_lds16(const void* g, void* l) {
    __builtin_amdgcn_global_load_lds(
        (const __attribute__((address_space(1))) void*)g,
        (__attribute__((address_space(3))) void*)l, 16, 0, 0);
}

// ---------------------------------------------------------------------------
// fused init + split: blocks x<1024 split f32 -> bf16 hi|lo; x>=1024 init
// augmented row/col of K0, K0hT, Kreg + c=1 + barrier slots/chg flags
// ---------------------------------------------------------------------------
__global__ __launch_bounds__(256) void init_split(const float* __restrict__ Q,
                                                  const float* __restrict__ Rm,
                                                  ushort* __restrict__ Qe,
                                                  ushort* __restrict__ Re,
                                                  float* __restrict__ Kreg,
                                                  _Float16* __restrict__ K0h,
                                                  _Float16* __restrict__ K0hT,
                                                  float* __restrict__ c,
                                                  unsigned* __restrict__ ctrl,
                                                  const float* __restrict__ zp) {
    if (blockIdx.x < 1024) {
        const float* src = blockIdx.y ? Rm : Q;
        ushort* dst = blockIdx.y ? Re : Qe;
        int e4 = blockIdx.x * 256 + threadIdx.x;    // float4 units
        int row = e4 >> 7;
        int c4 = (e4 & 127) * 4;
        float4 v = *(const float4*)(src + (size_t)row * DD + c4);
        ushort4 hi, lo;
        hi.x = f2bf(v.x); lo.x = f2bf(v.x - bf2f(hi.x));
        hi.y = f2bf(v.y); lo.y = f2bf(v.y - bf2f(hi.y));
        hi.z = f2bf(v.z); lo.z = f2bf(v.z - bf2f(hi.z));
        hi.w = f2bf(v.w); lo.w = f2bf(v.w - bf2f(hi.w));
        *(ushort4*)(dst + (size_t)row * LDE + c4) = hi;
        *(ushort4*)(dst + (size_t)row * LDE + 512 + c4) = lo;
    } else {
        float e5 = expf(zp[0] * 10.0f);   // exp(z/eps)
        int idx = (blockIdx.x - 1024) * 512 + blockIdx.y * 256 + threadIdx.x;
        for (int t = idx; t < NA; t += 1024) {
            if (t < 512) ctrl[t] = 0u;
            c[t] = 1.0f;
            Kreg[(size_t)2048 * NA + t] = e5;
            K0h [(size_t)2048 * LDH + t] = (_Float16)e5;
            K0hT[(size_t)2048 * LDH + t] = (_Float16)e5;
            if (t < MM) {
                Kreg[(size_t)t * NA + 2048] = e5;
                K0h [(size_t)t * LDH + 2048] = (_Float16)e5;
                K0hT[(size_t)t * LDH + 2048] = (_Float16)e5;
            }
        }
    }
}

// ---------------------------------------------------------------------------
// bf16 MFMA GEMM over K'=1024 (hi|lo concat) + exp epilogue.
// Writes f32 Kreg, fp16 K0h, AND fp16 K0hT (fused transpose).  [verified r5-14]
// ---------------------------------------------------------------------------
__global__ __launch_bounds__(256, 2) void gemm_mfma(const ushort* __restrict__ Ae,
                                                    const ushort* __restrict__ Be,
                                                    float* __restrict__ Kreg,
                                                    _Float16* __restrict__ K0h,
                                                    _Float16* __restrict__ K0hT) {
    __shared__ ushort Als[64 * 32];
    __shared__ ushort Bls[128 * 32];
    const int tid = threadIdx.x;
    const int wid = tid >> 6, lane = tid & 63;
    const int row0 = blockIdx.y * 64, col0 = blockIdx.x * 128;
    const int wr = wid >> 1, wc = wid & 1;

    const int sr = lane >> 2, sc = (lane & 3) * 8;
    const ushort* gA  = Ae + (size_t)(row0 + wid * 16 + sr) * LDE + sc;
    const ushort* gB0 = Be + (size_t)(col0 + wid * 16 + sr) * LDE + sc;
    const ushort* gB1 = Be + (size_t)(col0 + 64 + wid * 16 + sr) * LDE + sc;
    ushort* lA  = &Als[wid * 16 * 32];
    ushort* lB0 = &Bls[wid * 16 * 32];
    ushort* lB1 = &Bls[(64 + wid * 16) * 32];

    f32x4 acc[2][4] = {};
    const int fr = lane & 15, fk = (lane >> 4) * 8;

    for (int k0 = 0; k0 < 1024; k0 += 32) {
        __syncthreads();
        gload_lds16(gA + k0, lA);
        gload_lds16(gB0 + k0, lB0);
        gload_lds16(gB1 + k0, lB1);
        __syncthreads();
        short8 a[2], b[4];
#pragma unroll
        for (int mi = 0; mi < 2; ++mi)
            a[mi] = *(const short8*)&Als[(wr * 32 + mi * 16 + fr) * 32 + fk];
#pragma unroll
        for (int ni = 0; ni < 4; ++ni)
            b[ni] = *(const short8*)&Bls[(wc * 64 + ni * 16 + fr) * 32 + fk];
#pragma unroll
        for (int mi = 0; mi < 2; ++mi)
#pragma unroll
            for (int ni = 0; ni < 4; ++ni)
                acc[mi][ni] = __builtin_amdgcn_mfma_f32_16x16x32_bf16(
                    a[mi], b[ni], acc[mi][ni], 0, 0, 0);
    }

#pragma unroll
    for (int mi = 0; mi < 2; ++mi)
#pragma unroll
        for (int ni = 0; ni < 4; ++ni) {
            const int rowb = row0 + wr * 32 + mi * 16 + (lane >> 4) * 4;
            const int col  = col0 + wc * 64 + ni * 16 + fr;
            union { ushort4 u; _Float16 h[4]; } tp;
#pragma unroll
            for (int q = 0; q < 4; ++q) {
                float v = expf(acc[mi][ni][q] * 10.0f);
                Kreg[(size_t)(rowb + q) * NA + col] = v;
                _Float16 hv = (_Float16)v;
                K0h[(size_t)(rowb + q) * LDH + col] = hv;
                tp.h[q] = hv;
            }
            *(ushort4*)(K0hT + (size_t)col * LDH + rowb) = tp.u;  // 8B, aligned
        }
}

// ---------------------------------------------------------------------------
// persistent Sinkhorn loop — r10 proven config: flat slotted barrier,
// check+break+chg, fused finalize epilogue.  [barrier ledger: flat=best;
// tree r12 +150ns/phase; fan-out r14 +460ns/phase; no-check r8 = 27x slow]
// ---------------------------------------------------------------------------
__device__ __forceinline__ void grid_barrier(unsigned* slot) {
    __syncthreads();
    if (threadIdx.x == 0) {
        __hip_atomic_fetch_add(slot, 1u, __ATOMIC_ACQ_REL, __HIP_MEMORY_SCOPE_AGENT);
        while (__hip_atomic_load(slot, __ATOMIC_ACQUIRE, __HIP_MEMORY_SCOPE_AGENT)
               != (unsigned)NWG)
            __builtin_amdgcn_s_sleep(1);
    }
    __syncthreads();
}

__device__ __forceinline__ float rowdot(const _Float16* __restrict__ Krow,
                                        const float* v, int lane) {
    float sum = 0.0f;
#pragma unroll
    for (int s = 0; s < 4; ++s) {
        const int j = (s * 64 + lane) * 8;
        union { uint4 u; _Float16 h[8]; } kv;
        kv.u = *(const uint4*)(Krow + j);
        float4 c0 = *(const float4*)(v + j);
        float4 c1 = *(const float4*)(v + j + 4);
        sum += (float)kv.h[0] * c0.x + (float)kv.h[1] * c0.y +
               (float)kv.h[2] * c0.z + (float)kv.h[3] * c0.w +
               (float)kv.h[4] * c1.x + (float)kv.h[5] * c1.y +
               (float)kv.h[6] * c1.z + (float)kv.h[7] * c1.w;
    }
    if (lane == 0) sum += (float)Krow[2048] * v[2048];
#pragma unroll
    for (int off = 32; off; off >>= 1) sum += __shfl_xor(sum, off, 64);
    return sum;
}

__global__ __launch_bounds__(TPB) void sinkhorn_persist(
    const _Float16* __restrict__ K0h, const _Float16* __restrict__ K0hT,
    float* r, float* c, unsigned* slots, unsigned* chg,
    float* __restrict__ Kreg, float* __restrict__ P)
{
    const int wave = threadIdx.x >> 6, lane = threadIdx.x & 63;
    const int row = blockIdx.x * 8 + wave;
    const bool active = row < NA;
    const _Float16* KrowA = K0h  + (size_t)row * LDH;
    const _Float16* KrowB = K0hT + (size_t)row * LDH;
    __shared__ int ls_chg, ls_exit;
    float c_prev = 1.0f;

    for (int it = 0; it < ITERS; ++it) {
        if (threadIdx.x == 0) ls_chg = 0;
        // phase 1: r = 1 / (K0 c)
        if (active) {
            float s = rowdot(KrowA, c, lane);
            if (lane == 0) r[row] = 1.0f / s;
        }
        grid_barrier(&slots[2 * it]);
        // phase 2: c = 1 / (K0^T r)
        float cv = 0.0f;
        if (active) {
            float s = rowdot(KrowB, r, lane);
            cv = 1.0f / s;
            if (lane == 0) c[row] = cv;
        }
        if (active && lane == 0) {
            if (fabsf(cv - c_prev) > 1e-6f * fabsf(c_prev)) ls_chg = 1;
            c_prev = cv;
        }
        __syncthreads();
        if (threadIdx.x == 0 && ls_chg)
            __hip_atomic_fetch_or(&chg[it], 1u, __ATOMIC_RELAXED,
                                  __HIP_MEMORY_SCOPE_AGENT);
        grid_barrier(&slots[2 * it + 1]);
        if (threadIdx.x == 0)
            ls_exit = (__hip_atomic_load(&chg[it], __ATOMIC_RELAXED,
                                         __HIP_MEMORY_SCOPE_AGENT) == 0u);
        __syncthreads();
        if (ls_exit) break;
    }

    // ---- fused finalize: K = diag(r) K0 diag(c), P = K[:M,:N] ----
    if (active) {
        const float rs = r[row];
        float* krow = Kreg + (size_t)row * NA;
        float* prow = P + (size_t)row * NN;
        if (row < MM) {
            for (int col = lane; col < NN; col += 64) {
                float v = krow[col] * rs * c[col];
                krow[col] = v;
                prow[col] = v;
            }
            if (lane == 0) krow[2048] = krow[2048] * rs * c[2048];
        } else {
            for (int col = lane; col < NA; col += 64)
                krow[col] = krow[col] * rs * c[col];
        }
    }
}

// ---------------------------------------------------------------------------
extern "C" void kernel_launch(void* const* d_in, const int* in_sizes, int n_in,
                              void* d_out, int out_size, void* d_ws, size_t ws_size,
                              hipStream_t stream) {
    const float* Q  = (const float*)d_in[0];
    const float* Rm = (const float*)d_in[1];
    const float* zp = (const float*)d_in[2];

    float* P    = (float*)d_out;
    float* Kreg = P + (size_t)MM * NN;

    ushort* Qe = (ushort*)d_out;                 // staged in P region (dead by epilogue)
    ushort* Re = Qe + (size_t)2048 * LDE;

    char* ws = (char*)d_ws;
    const size_t HBYTES = 8425728;               // NA*LDH*2 rounded to 256
    _Float16* K0h  = (_Float16*)ws;
    _Float16* K0hT = (_Float16*)(ws + HBYTES);
    float* c = (float*)(ws + 2 * HBYTES);
    float* r = c + 2560;
    unsigned* ctrl = (unsigned*)(r + 2560);
    unsigned* slots = ctrl;                      // [0..255] barrier slots
    unsigned* chg   = ctrl + 256;                // [256..355] per-iter flags

    init_split<<<dim3(1026, 2), dim3(256), 0, stream>>>(Q, Rm, Qe, Re, Kreg,
                                                        K0h, K0hT, c, ctrl, zp);
    gemm_mfma<<<dim3(16, 32), dim3(256), 0, stream>>>(Qe, Re, Kreg, K0h, K0hT);
    sinkhorn_persist<<<dim3(NWG), dim3(TPB), 0, stream>>>(K0h, K0hT, r, c,
                                                          slots, chg, Kreg, P);
}